// Round 1
// baseline (557.287 us; speedup 1.0000x reference)
//
#include <hip/hip_runtime.h>

#define EPS 1e-5f

typedef __attribute__((ext_vector_type(8))) short bf16x8;   // MFMA A/B frag (8 bf16)
typedef __attribute__((ext_vector_type(4))) float f32x4;    // MFMA C/D frag
typedef __attribute__((ext_vector_type(4))) unsigned short us4;
typedef __attribute__((ext_vector_type(8))) unsigned short us8;

__device__ __forceinline__ unsigned short f2bf(float f) {
    union { float f; unsigned int u; } c; c.f = f;
    unsigned int u = c.u;
    u += 0x7fffu + ((u >> 16) & 1u);
    return (unsigned short)(u >> 16);
}

__device__ __forceinline__ int swz(int byte, int col) { return byte ^ ((col & 7) << 4); }

// ws layout (bytes):
//   [0,1536)        W1f   384 f32  (BN1-folded W1)
//   [1536,2048)     b1p   128 f32
//   [2048,4096)     b3p   512 f32  (BN3-folded bias)
//   [4096,69632)    W2b   256x128 bf16
//   [69632,593920)  W3b   512x512 bf16 (BN3-folded)
//   [593920,987136) W4b   384x512 bf16

__global__ void prep_kernel(const float* __restrict__ W1, const float* __restrict__ b1,
                            const float* __restrict__ g1, const float* __restrict__ be1,
                            const float* __restrict__ m1, const float* __restrict__ v1,
                            const float* __restrict__ W2,
                            const float* __restrict__ W3, const float* __restrict__ b3,
                            const float* __restrict__ g3, const float* __restrict__ be3,
                            const float* __restrict__ m3, const float* __restrict__ v3,
                            const float* __restrict__ W4,
                            char* __restrict__ ws)
{
    float* W1f = (float*)ws;
    float* b1p = (float*)(ws + 1536);
    float* b3p = (float*)(ws + 2048);
    unsigned short* W2b = (unsigned short*)(ws + 4096);
    unsigned short* W3b = (unsigned short*)(ws + 69632);
    unsigned short* W4b = (unsigned short*)(ws + 593920);

    const int stride = gridDim.x * blockDim.x;
    for (int idx = blockIdx.x * blockDim.x + threadIdx.x; idx < 262144; idx += stride) {
        {
            int c = idx >> 9;
            float inv = g3[c] / sqrtf(v3[c] + EPS);
            W3b[idx] = f2bf(W3[idx] * inv);
        }
        if (idx < 196608) W4b[idx] = f2bf(W4[idx]);
        if (idx < 32768)  W2b[idx] = f2bf(W2[idx]);
        if (idx < 384) {
            int c = idx / 3;
            float inv = g1[c] / sqrtf(v1[c] + EPS);
            W1f[idx] = W1[idx] * inv;
        }
        if (idx < 128) {
            float inv = g1[idx] / sqrtf(v1[idx] + EPS);
            b1p[idx] = b1[idx] * inv + be1[idx] - m1[idx] * inv;
        }
        if (idx < 512) {
            float inv = g3[idx] / sqrtf(v3[idx] + EPS);
            b3p[idx] = b3[idx] * inv + be3[idx] - m3[idx] * inv;
        }
    }
}

__global__ __launch_bounds__(512, 2)
void patch_kernel(const float* __restrict__ pg,
                  const float* __restrict__ b2,
                  const float* __restrict__ b4,
                  const char* __restrict__ ws,
                  float* __restrict__ out)
{
    const float* W1f = (const float*)ws;
    const float* b1p = (const float*)(ws + 1536);
    const float* b3p = (const float*)(ws + 2048);
    const unsigned short* W2b = (const unsigned short*)(ws + 4096);
    const unsigned short* W3b = (const unsigned short*)(ws + 69632);
    const unsigned short* W4b = (const unsigned short*)(ws + 593920);

    __shared__ unsigned short s_hT[64 * 128];    // 16 KB  [col][128]
    __shared__ unsigned short s_comb[64 * 512];  // 64 KB  [col][512] (0:256 gf, 256:512 pf)
    __shared__ unsigned short s_h2[64 * 512];    // 64 KB  [col][512]

    const int tid  = (int)threadIdx.x;
    const int wave = tid >> 6;
    const int lane = tid & 63;
    const int l15  = lane & 15;
    const int lq   = lane >> 4;
    const int n0   = (int)blockIdx.x * 2;

    // ---- Layer 1 (fp32) ----
    {
        const int col = lane;
        const int g = col >> 5, k = col & 31;
        const float* xp = pg + ((size_t)(n0 + g) * 32 + k) * 3;
        const float x0 = xp[0], x1 = xp[1], x2 = xp[2];
        const int c0 = wave * 16;
        us8 p0, p1;
        #pragma unroll
        for (int j = 0; j < 16; ++j) {
            const int c = c0 + j;
            float v = fmaf(W1f[c*3+0], x0, fmaf(W1f[c*3+1], x1, fmaf(W1f[c*3+2], x2, b1p[c])));
            v = fmaxf(v, 0.f);
            if (j < 8) p0[j] = f2bf(v); else p1[j-8] = f2bf(v);
        }
        char* hb = (char*)s_hT;
        *(us8*)(hb + swz(col*256 + c0*2,      col)) = p0;
        *(us8*)(hb + swz(col*256 + c0*2 + 16, col)) = p1;
    }
    __syncthreads();

    // ---- Layer 2 (MFMA): pf + wave-local max -> gf ----
    {
        f32x4 acc[2][4];
        #pragma unroll
        for (int mt = 0; mt < 2; ++mt)
            #pragma unroll
            for (int nt = 0; nt < 4; ++nt)
                acc[mt][nt] = (f32x4){0.f, 0.f, 0.f, 0.f};

        #pragma unroll
        for (int ks = 0; ks < 4; ++ks) {
            bf16x8 A[2], Bv[4];
            #pragma unroll
            for (int mt = 0; mt < 2; ++mt) {
                const int row = (wave*2 + mt)*16 + l15;
                A[mt] = *(const bf16x8*)(W2b + row*128 + ks*32 + lq*8);
            }
            #pragma unroll
            for (int nt = 0; nt < 4; ++nt) {
                const int col = nt*16 + l15;
                Bv[nt] = *(const bf16x8*)((const char*)s_hT + swz(col*256 + ks*64 + lq*16, col));
            }
            #pragma unroll
            for (int mt = 0; mt < 2; ++mt)
                #pragma unroll
                for (int nt = 0; nt < 4; ++nt)
                    acc[mt][nt] = __builtin_amdgcn_mfma_f32_16x16x32_bf16(A[mt], Bv[nt], acc[mt][nt], 0, 0, 0);
        }

        #pragma unroll
        for (int mt = 0; mt < 2; ++mt) {
            const int row0 = (wave*2 + mt)*16 + lq*4;
            float bias[4];
            #pragma unroll
            for (int r = 0; r < 4; ++r) bias[r] = b2[row0 + r];
            float gmax[2][4];
            #pragma unroll
            for (int nt = 0; nt < 4; ++nt) {
                const int col = nt*16 + l15;
                const int g = nt >> 1;
                us4 p;
                #pragma unroll
                for (int r = 0; r < 4; ++r) {
                    float v = acc[mt][nt][r] + bias[r];
                    p[r] = f2bf(v);
                    if ((nt & 1) == 0) gmax[g][r] = v; else gmax[g][r] = fmaxf(gmax[g][r], v);
                }
                *(us4*)((char*)s_comb + swz(col*1024 + (256 + row0)*2, col)) = p;
            }
            #pragma unroll
            for (int m = 1; m < 16; m <<= 1)
                #pragma unroll
                for (int g = 0; g < 2; ++g)
                    #pragma unroll
                    for (int r = 0; r < 4; ++r)
                        gmax[g][r] = fmaxf(gmax[g][r], __shfl_xor(gmax[g][r], m));
            #pragma unroll
            for (int g = 0; g < 2; ++g) {
                us4 q;
                #pragma unroll
                for (int r = 0; r < 4; ++r) q[r] = f2bf(gmax[g][r]);
                const int c0 = g*32 + l15;
                const int c1 = c0 + 16;
                *(us4*)((char*)s_comb + swz(c0*1024 + row0*2, c0)) = q;
                *(us4*)((char*)s_comb + swz(c1*1024 + row0*2, c1)) = q;
            }
        }
    }
    __syncthreads();

    // ---- Layer 3 (MFMA): h2 = relu(W3' comb + b3p) ----
    {
        f32x4 acc[4][4];
        #pragma unroll
        for (int mt = 0; mt < 4; ++mt)
            #pragma unroll
            for (int nt = 0; nt < 4; ++nt)
                acc[mt][nt] = (f32x4){0.f, 0.f, 0.f, 0.f};

        #pragma unroll 2
        for (int ks = 0; ks < 16; ++ks) {
            bf16x8 A[4], Bv[4];
            #pragma unroll
            for (int mt = 0; mt < 4; ++mt) {
                const int row = (wave*4 + mt)*16 + l15;
                A[mt] = *(const bf16x8*)(W3b + row*512 + ks*32 + lq*8);
            }
            #pragma unroll
            for (int nt = 0; nt < 4; ++nt) {
                const int col = nt*16 + l15;
                Bv[nt] = *(const bf16x8*)((const char*)s_comb + swz(col*1024 + ks*64 + lq*16, col));
            }
            #pragma unroll
            for (int mt = 0; mt < 4; ++mt)
                #pragma unroll
                for (int nt = 0; nt < 4; ++nt)
                    acc[mt][nt] = __builtin_amdgcn_mfma_f32_16x16x32_bf16(A[mt], Bv[nt], acc[mt][nt], 0, 0, 0);
        }

        #pragma unroll
        for (int mt = 0; mt < 4; ++mt) {
            const int row0 = (wave*4 + mt)*16 + lq*4;
            float bias[4];
            #pragma unroll
            for (int r = 0; r < 4; ++r) bias[r] = b3p[row0 + r];
            #pragma unroll
            for (int nt = 0; nt < 4; ++nt) {
                const int col = nt*16 + l15;
                us4 p;
                #pragma unroll
                for (int r = 0; r < 4; ++r) p[r] = f2bf(fmaxf(acc[mt][nt][r] + bias[r], 0.f));
                *(us4*)((char*)s_h2 + swz(col*1024 + row0*2, col)) = p;
            }
        }
    }
    __syncthreads();

    // ---- Layer 4 (MFMA): out = max_k (W4 h2 + b4) ----
    {
        f32x4 acc[3][4];
        #pragma unroll
        for (int mt = 0; mt < 3; ++mt)
            #pragma unroll
            for (int nt = 0; nt < 4; ++nt)
                acc[mt][nt] = (f32x4){0.f, 0.f, 0.f, 0.f};

        #pragma unroll 2
        for (int ks = 0; ks < 16; ++ks) {
            bf16x8 A[3], Bv[4];
            #pragma unroll
            for (int mt = 0; mt < 3; ++mt) {
                const int row = (wave*3 + mt)*16 + l15;
                A[mt] = *(const bf16x8*)(W4b + row*512 + ks*32 + lq*8);
            }
            #pragma unroll
            for (int nt = 0; nt < 4; ++nt) {
                const int col = nt*16 + l15;
                Bv[nt] = *(const bf16x8*)((const char*)s_h2 + swz(col*1024 + ks*64 + lq*16, col));
            }
            #pragma unroll
            for (int mt = 0; mt < 3; ++mt)
                #pragma unroll
                for (int nt = 0; nt < 4; ++nt)
                    acc[mt][nt] = __builtin_amdgcn_mfma_f32_16x16x32_bf16(A[mt], Bv[nt], acc[mt][nt], 0, 0, 0);
        }

        #pragma unroll
        for (int mt = 0; mt < 3; ++mt) {
            const int row0 = (wave*3 + mt)*16 + lq*4;
            float bias[4];
            #pragma unroll
            for (int r = 0; r < 4; ++r) bias[r] = b4[row0 + r];
            float gmax[2][4];
            #pragma unroll
            for (int nt = 0; nt < 4; ++nt) {
                const int g = nt >> 1;
                #pragma unroll
                for (int r = 0; r < 4; ++r) {
                    float v = acc[mt][nt][r] + bias[r];
                    if ((nt & 1) == 0) gmax[g][r] = v; else gmax[g][r] = fmaxf(gmax[g][r], v);
                }
            }
            #pragma unroll
            for (int m = 1; m < 16; m <<= 1)
                #pragma unroll
                for (int g = 0; g < 2; ++g)
                    #pragma unroll
                    for (int r = 0; r < 4; ++r)
                        gmax[g][r] = fmaxf(gmax[g][r], __shfl_xor(gmax[g][r], m));
            if (l15 < 2) {
                const int g = l15;
                f32x4 o;
                #pragma unroll
                for (int r = 0; r < 4; ++r) o[r] = gmax[g][r];
                *(f32x4*)(out + (size_t)(n0 + g) * 384 + row0) = o;
            }
        }
    }
}

extern "C" void kernel_launch(void* const* d_in, const int* in_sizes, int n_in,
                              void* d_out, int out_size, void* d_ws, size_t ws_size,
                              hipStream_t stream) {
    const float* pg  = (const float*)d_in[0];
    const float* W1  = (const float*)d_in[1];
    const float* b1  = (const float*)d_in[2];
    const float* g1  = (const float*)d_in[3];
    const float* be1 = (const float*)d_in[4];
    const float* m1  = (const float*)d_in[5];
    const float* v1  = (const float*)d_in[6];
    const float* W2  = (const float*)d_in[7];
    const float* b2  = (const float*)d_in[8];
    const float* W3  = (const float*)d_in[9];
    const float* b3  = (const float*)d_in[10];
    const float* g3  = (const float*)d_in[11];
    const float* be3 = (const float*)d_in[12];
    const float* m3  = (const float*)d_in[13];
    const float* v3  = (const float*)d_in[14];
    const float* W4  = (const float*)d_in[15];
    const float* b4  = (const float*)d_in[16];
    float* out = (float*)d_out;
    char* ws = (char*)d_ws;

    prep_kernel<<<dim3(256), dim3(256), 0, stream>>>(W1, b1, g1, be1, m1, v1, W2,
                                                     W3, b3, g3, be3, m3, v3, W4, ws);
    patch_kernel<<<dim3(4096), dim3(512), 0, stream>>>(pg, b2, b4, ws, out);
    (void)in_sizes; (void)n_in; (void)out_size; (void)ws_size;
}

// Round 2
// 481.292 us; speedup vs baseline: 1.1579x; 1.1579x over previous
//
#include <hip/hip_runtime.h>

#define EPS 1e-5f

typedef __attribute__((ext_vector_type(8))) short bf16x8;   // MFMA A/B frag (8 bf16)
typedef __attribute__((ext_vector_type(4))) float f32x4;    // MFMA C/D frag
typedef __attribute__((ext_vector_type(4))) unsigned short us4;
typedef __attribute__((ext_vector_type(8))) unsigned short us8;

__device__ __forceinline__ unsigned short f2bf(float f) {
    union { float f; unsigned int u; } c; c.f = f;
    unsigned int u = c.u;
    u += 0x7fffu + ((u >> 16) & 1u);
    return (unsigned short)(u >> 16);
}
__device__ __forceinline__ float bf2f(unsigned short h) {
    union { unsigned int u; float f; } c; c.u = ((unsigned int)h) << 16;
    return c.f;
}
__device__ __forceinline__ int swz(int byte, int col) { return byte ^ ((col & 7) << 4); }

// ws layout (bytes):
//   [0,1536)        W1f   384 f32  (BN1-folded W1)
//   [1536,2048)     b1p   128 f32
//   [2048,4096)     b3p   512 f32  (BN3-folded bias)
//   [4096,69632)    W2b   256x128 bf16
//   [69632,593920)  W3b   512x512 bf16 (BN3-folded; cols 0:256 = gf part, 256:512 = pf part)
//   [593920,987136) W4b   384x512 bf16

__global__ void prep_kernel(const float* __restrict__ W1, const float* __restrict__ b1,
                            const float* __restrict__ g1, const float* __restrict__ be1,
                            const float* __restrict__ m1, const float* __restrict__ v1,
                            const float* __restrict__ W2,
                            const float* __restrict__ W3, const float* __restrict__ b3,
                            const float* __restrict__ g3, const float* __restrict__ be3,
                            const float* __restrict__ m3, const float* __restrict__ v3,
                            const float* __restrict__ W4,
                            char* __restrict__ ws)
{
    float* W1f = (float*)ws;
    float* b1p = (float*)(ws + 1536);
    float* b3p = (float*)(ws + 2048);
    unsigned short* W2b = (unsigned short*)(ws + 4096);
    unsigned short* W3b = (unsigned short*)(ws + 69632);
    unsigned short* W4b = (unsigned short*)(ws + 593920);

    const int stride = gridDim.x * blockDim.x;
    for (int idx = blockIdx.x * blockDim.x + threadIdx.x; idx < 262144; idx += stride) {
        {
            int c = idx >> 9;
            float inv = g3[c] / sqrtf(v3[c] + EPS);
            W3b[idx] = f2bf(W3[idx] * inv);
        }
        if (idx < 196608) W4b[idx] = f2bf(W4[idx]);
        if (idx < 32768)  W2b[idx] = f2bf(W2[idx]);
        if (idx < 384) {
            int c = idx / 3;
            float inv = g1[c] / sqrtf(v1[c] + EPS);
            W1f[idx] = W1[idx] * inv;
        }
        if (idx < 128) {
            float inv = g1[idx] / sqrtf(v1[idx] + EPS);
            b1p[idx] = b1[idx] * inv + be1[idx] - m1[idx] * inv;
        }
        if (idx < 512) {
            float inv = g3[idx] / sqrtf(v3[idx] + EPS);
            b3p[idx] = b3[idx] * inv + be3[idx] - m3[idx] * inv;
        }
    }
}

// LDS map (68 KB total, 2 blocks/CU):
//   HT  [0, 16K)      : hT   64 cols x 128 ch bf16 (stride 256B)   live L1->L2
//   PF  [16K, 48K)    : pf   64 cols x 256 ch bf16 (stride 512B)   live L2->L3 mfma
//   GF  [48K, 50K)    : gf   2 groups x 256 f32                    live L2->matvec
//   H2  [0, 64K)      : h2   64 cols x 512 ch bf16 (stride 1024B)  ALIASES HT/PF/GF,
//                       written only after the post-L3 barrier
//   U   [64K, 68K)    : u    2 groups x 512 f32 (W3a @ gf)
#define OFF_HT 0
#define OFF_PF 16384
#define OFF_GF 49152
#define OFF_H2 0
#define OFF_U  65536
#define SMEM_BYTES 69632

__global__ __launch_bounds__(512, 4)
void patch_kernel(const float* __restrict__ pg,
                  const float* __restrict__ b2,
                  const float* __restrict__ b4,
                  const char* __restrict__ ws,
                  float* __restrict__ out)
{
    const float* W1f = (const float*)ws;
    const float* b1p = (const float*)(ws + 1536);
    const float* b3p = (const float*)(ws + 2048);
    const unsigned short* W2b = (const unsigned short*)(ws + 4096);
    const unsigned short* W3b = (const unsigned short*)(ws + 69632);
    const unsigned short* W4b = (const unsigned short*)(ws + 593920);

    __shared__ char smem[SMEM_BYTES];

    const int tid  = (int)threadIdx.x;
    const int wave = tid >> 6;
    const int lane = tid & 63;
    const int l15  = lane & 15;
    const int lq   = lane >> 4;
    const int n0   = (int)blockIdx.x * 2;

    // ---- Layer 1 (fp32): hT[col][128] ----
    {
        const int col = lane;
        const int g = col >> 5, k = col & 31;
        const float* xp = pg + ((size_t)(n0 + g) * 32 + k) * 3;
        const float x0 = xp[0], x1 = xp[1], x2 = xp[2];
        const int c0 = wave * 16;
        us8 p0, p1;
        #pragma unroll
        for (int j = 0; j < 16; ++j) {
            const int c = c0 + j;
            float v = fmaf(W1f[c*3+0], x0, fmaf(W1f[c*3+1], x1, fmaf(W1f[c*3+2], x2, b1p[c])));
            v = fmaxf(v, 0.f);
            if (j < 8) p0[j] = f2bf(v); else p1[j-8] = f2bf(v);
        }
        *(us8*)(smem + OFF_HT + swz(col*256 + c0*2,      col)) = p0;
        *(us8*)(smem + OFF_HT + swz(col*256 + c0*2 + 16, col)) = p1;
    }
    __syncthreads();

    // ---- Layer 2 (MFMA): pf[col][256] + per-group max -> gf ----
    {
        f32x4 acc[2][4];
        #pragma unroll
        for (int mt = 0; mt < 2; ++mt)
            #pragma unroll
            for (int nt = 0; nt < 4; ++nt)
                acc[mt][nt] = (f32x4){0.f, 0.f, 0.f, 0.f};

        #pragma unroll
        for (int ks = 0; ks < 4; ++ks) {
            bf16x8 A[2], Bv[4];
            #pragma unroll
            for (int mt = 0; mt < 2; ++mt) {
                const int row = (wave*2 + mt)*16 + l15;
                A[mt] = *(const bf16x8*)(W2b + row*128 + ks*32 + lq*8);
            }
            #pragma unroll
            for (int nt = 0; nt < 4; ++nt) {
                const int col = nt*16 + l15;
                Bv[nt] = *(const bf16x8*)(smem + OFF_HT + swz(col*256 + ks*64 + lq*16, col));
            }
            #pragma unroll
            for (int mt = 0; mt < 2; ++mt)
                #pragma unroll
                for (int nt = 0; nt < 4; ++nt)
                    acc[mt][nt] = __builtin_amdgcn_mfma_f32_16x16x32_bf16(A[mt], Bv[nt], acc[mt][nt], 0, 0, 0);
        }

        #pragma unroll
        for (int mt = 0; mt < 2; ++mt) {
            const int row0 = (wave*2 + mt)*16 + lq*4;
            float bias[4];
            #pragma unroll
            for (int r = 0; r < 4; ++r) bias[r] = b2[row0 + r];
            float gmax[2][4];
            #pragma unroll
            for (int nt = 0; nt < 4; ++nt) {
                const int col = nt*16 + l15;
                const int g = nt >> 1;
                us4 p;
                #pragma unroll
                for (int r = 0; r < 4; ++r) {
                    float v = acc[mt][nt][r] + bias[r];
                    p[r] = f2bf(v);
                    if ((nt & 1) == 0) gmax[g][r] = v; else gmax[g][r] = fmaxf(gmax[g][r], v);
                }
                *(us4*)(smem + OFF_PF + swz(col*512 + row0*2, col)) = p;
            }
            #pragma unroll
            for (int m = 1; m < 16; m <<= 1)
                #pragma unroll
                for (int g = 0; g < 2; ++g)
                    #pragma unroll
                    for (int r = 0; r < 4; ++r)
                        gmax[g][r] = fmaxf(gmax[g][r], __shfl_xor(gmax[g][r], m));
            if (l15 < 2) {
                const int g = l15;
                f32x4 q;
                #pragma unroll
                for (int r = 0; r < 4; ++r) q[r] = gmax[g][r];
                *(f32x4*)(smem + OFF_GF + (g*256 + row0)*4) = q;
            }
        }
    }
    __syncthreads();

    // ---- matvec: u[g][r] = W3a[r,:] @ gf[g]   (rank-1 part of the concat) ----
    {
        const unsigned short* w3row = W3b + (size_t)tid * 512;  // cols 0..255 = gf part
        const float* gf0 = (const float*)(smem + OFF_GF);
        const float* gf1 = gf0 + 256;
        float a0 = 0.f, a1 = 0.f;
        #pragma unroll 4
        for (int c = 0; c < 256; c += 8) {
            us8 w = *(const us8*)(w3row + c);
            f32x4 g0a = *(const f32x4*)(gf0 + c), g0b = *(const f32x4*)(gf0 + c + 4);
            f32x4 g1a = *(const f32x4*)(gf1 + c), g1b = *(const f32x4*)(gf1 + c + 4);
            #pragma unroll
            for (int j = 0; j < 4; ++j) {
                float wa = bf2f(w[j]), wb = bf2f(w[j+4]);
                a0 = fmaf(wa, g0a[j], a0); a0 = fmaf(wb, g0b[j], a0);
                a1 = fmaf(wa, g1a[j], a1); a1 = fmaf(wb, g1b[j], a1);
            }
        }
        float* u = (float*)(smem + OFF_U);
        u[tid] = a0;
        u[512 + tid] = a1;
    }

    // ---- Layer 3 (MFMA, K=256 over pf only): acc then (after barrier) h2 ----
    {
        f32x4 acc[4][4];
        #pragma unroll
        for (int mt = 0; mt < 4; ++mt)
            #pragma unroll
            for (int nt = 0; nt < 4; ++nt)
                acc[mt][nt] = (f32x4){0.f, 0.f, 0.f, 0.f};

        #pragma unroll 2
        for (int ks = 0; ks < 8; ++ks) {
            bf16x8 A[4], Bv[4];
            #pragma unroll
            for (int mt = 0; mt < 4; ++mt) {
                const int row = (wave*4 + mt)*16 + l15;
                A[mt] = *(const bf16x8*)(W3b + row*512 + 256 + ks*32 + lq*8);
            }
            #pragma unroll
            for (int nt = 0; nt < 4; ++nt) {
                const int col = nt*16 + l15;
                Bv[nt] = *(const bf16x8*)(smem + OFF_PF + swz(col*512 + ks*64 + lq*16, col));
            }
            #pragma unroll
            for (int mt = 0; mt < 4; ++mt)
                #pragma unroll
                for (int nt = 0; nt < 4; ++nt)
                    acc[mt][nt] = __builtin_amdgcn_mfma_f32_16x16x32_bf16(A[mt], Bv[nt], acc[mt][nt], 0, 0, 0);
        }

        // all pf/gf reads done; publish u; then h2 may overwrite the aliased region
        __syncthreads();

        const float* u = (const float*)(smem + OFF_U);
        #pragma unroll
        for (int mt = 0; mt < 4; ++mt) {
            const int row0 = (wave*4 + mt)*16 + lq*4;
            float bias[2][4];
            #pragma unroll
            for (int r = 0; r < 4; ++r) {
                float b = b3p[row0 + r];
                bias[0][r] = b + u[row0 + r];
                bias[1][r] = b + u[512 + row0 + r];
            }
            #pragma unroll
            for (int nt = 0; nt < 4; ++nt) {
                const int col = nt*16 + l15;
                const int g = nt >> 1;
                us4 p;
                #pragma unroll
                for (int r = 0; r < 4; ++r)
                    p[r] = f2bf(fmaxf(acc[mt][nt][r] + bias[g][r], 0.f));
                *(us4*)(smem + OFF_H2 + swz(col*1024 + row0*2, col)) = p;
            }
        }
    }
    __syncthreads();

    // ---- Layer 4 (MFMA): out = max_k (W4 h2 + b4) ----
    {
        f32x4 acc[3][4];
        #pragma unroll
        for (int mt = 0; mt < 3; ++mt)
            #pragma unroll
            for (int nt = 0; nt < 4; ++nt)
                acc[mt][nt] = (f32x4){0.f, 0.f, 0.f, 0.f};

        #pragma unroll 2
        for (int ks = 0; ks < 16; ++ks) {
            bf16x8 A[3], Bv[4];
            #pragma unroll
            for (int mt = 0; mt < 3; ++mt) {
                const int row = (wave*3 + mt)*16 + l15;
                A[mt] = *(const bf16x8*)(W4b + row*512 + ks*32 + lq*8);
            }
            #pragma unroll
            for (int nt = 0; nt < 4; ++nt) {
                const int col = nt*16 + l15;
                Bv[nt] = *(const bf16x8*)(smem + OFF_H2 + swz(col*1024 + ks*64 + lq*16, col));
            }
            #pragma unroll
            for (int mt = 0; mt < 3; ++mt)
                #pragma unroll
                for (int nt = 0; nt < 4; ++nt)
                    acc[mt][nt] = __builtin_amdgcn_mfma_f32_16x16x32_bf16(A[mt], Bv[nt], acc[mt][nt], 0, 0, 0);
        }

        #pragma unroll
        for (int mt = 0; mt < 3; ++mt) {
            const int row0 = (wave*3 + mt)*16 + lq*4;
            float bias[4];
            #pragma unroll
            for (int r = 0; r < 4; ++r) bias[r] = b4[row0 + r];
            float gmax[2][4];
            #pragma unroll
            for (int nt = 0; nt < 4; ++nt) {
                const int g = nt >> 1;
                #pragma unroll
                for (int r = 0; r < 4; ++r) {
                    float v = acc[mt][nt][r] + bias[r];
                    if ((nt & 1) == 0) gmax[g][r] = v; else gmax[g][r] = fmaxf(gmax[g][r], v);
                }
            }
            #pragma unroll
            for (int m = 1; m < 16; m <<= 1)
                #pragma unroll
                for (int g = 0; g < 2; ++g)
                    #pragma unroll
                    for (int r = 0; r < 4; ++r)
                        gmax[g][r] = fmaxf(gmax[g][r], __shfl_xor(gmax[g][r], m));
            if (l15 < 2) {
                const int g = l15;
                f32x4 o;
                #pragma unroll
                for (int r = 0; r < 4; ++r) o[r] = gmax[g][r];
                *(f32x4*)(out + (size_t)(n0 + g) * 384 + row0) = o;
            }
        }
    }
}

extern "C" void kernel_launch(void* const* d_in, const int* in_sizes, int n_in,
                              void* d_out, int out_size, void* d_ws, size_t ws_size,
                              hipStream_t stream) {
    const float* pg  = (const float*)d_in[0];
    const float* W1  = (const float*)d_in[1];
    const float* b1  = (const float*)d_in[2];
    const float* g1  = (const float*)d_in[3];
    const float* be1 = (const float*)d_in[4];
    const float* m1  = (const float*)d_in[5];
    const float* v1  = (const float*)d_in[6];
    const float* W2  = (const float*)d_in[7];
    const float* b2  = (const float*)d_in[8];
    const float* W3  = (const float*)d_in[9];
    const float* b3  = (const float*)d_in[10];
    const float* g3  = (const float*)d_in[11];
    const float* be3 = (const float*)d_in[12];
    const float* m3  = (const float*)d_in[13];
    const float* v3  = (const float*)d_in[14];
    const float* W4  = (const float*)d_in[15];
    const float* b4  = (const float*)d_in[16];
    float* out = (float*)d_out;
    char* ws = (char*)d_ws;

    prep_kernel<<<dim3(256), dim3(256), 0, stream>>>(W1, b1, g1, be1, m1, v1, W2,
                                                     W3, b3, g3, be3, m3, v3, W4, ws);
    patch_kernel<<<dim3(4096), dim3(512), 0, stream>>>(pg, b2, b4, ws, out);
    (void)in_sizes; (void)n_in; (void)out_size; (void)ws_size;
}

// Round 3
// 345.343 us; speedup vs baseline: 1.6137x; 1.3937x over previous
//
#include <hip/hip_runtime.h>

#define EPS 1e-5f

typedef __attribute__((ext_vector_type(8))) short bf16x8;   // MFMA A/B frag (8 bf16)
typedef __attribute__((ext_vector_type(4))) float f32x4;    // MFMA C/D frag
typedef __attribute__((ext_vector_type(4))) unsigned short us4;
typedef __attribute__((ext_vector_type(8))) unsigned short us8;

__device__ __forceinline__ unsigned short f2bf(float f) {
    union { float f; unsigned int u; } c; c.f = f;
    unsigned int u = c.u;
    u += 0x7fffu + ((u >> 16) & 1u);
    return (unsigned short)(u >> 16);
}

// ws layout (bytes) — weights stored FRAGMENT-MAJOR:
//   frag index for element (row,col), K-tiles NKS=K/32:
//     dst = (((row>>4)*NKS + (col>>5))*64 + ((col>>3)&3)*16 + (row&15))*8 + (col&7)
//   so a wave's A-frag load is W + (rowblk*NKS + ks)*512 + lane*8  (contiguous 1KB)
//   [0,1536)        W1f   384 f32  (BN1-folded W1)
//   [1536,2048)     b1p   128 f32
//   [2048,4096)     b3p   512 f32  (BN3-folded bias)
//   [4096,69632)    W2f   256x128 bf16 frag  (NKS=4)
//   [69632,593920)  W3f   512x512 bf16 frag  (NKS=16; ks 0..7 = gf cols, 8..15 = pf cols)
//   [593920,987136) W4f   384x512 bf16 frag  (NKS=16)

__global__ void prep_kernel(const float* __restrict__ W1, const float* __restrict__ b1,
                            const float* __restrict__ g1, const float* __restrict__ be1,
                            const float* __restrict__ m1, const float* __restrict__ v1,
                            const float* __restrict__ W2,
                            const float* __restrict__ W3, const float* __restrict__ b3,
                            const float* __restrict__ g3, const float* __restrict__ be3,
                            const float* __restrict__ m3, const float* __restrict__ v3,
                            const float* __restrict__ W4,
                            char* __restrict__ ws)
{
    float* W1f = (float*)ws;
    float* b1p = (float*)(ws + 1536);
    float* b3p = (float*)(ws + 2048);
    unsigned short* W2b = (unsigned short*)(ws + 4096);
    unsigned short* W3b = (unsigned short*)(ws + 69632);
    unsigned short* W4b = (unsigned short*)(ws + 593920);

    const int stride = gridDim.x * blockDim.x;
    for (int idx = blockIdx.x * blockDim.x + threadIdx.x; idx < 262144; idx += stride) {
        {
            int row = idx >> 9, col = idx & 511;
            float inv = g3[row] / sqrtf(v3[row] + EPS);
            int dst = (((row >> 4) * 16 + (col >> 5)) * 64 + ((col >> 3) & 3) * 16 + (row & 15)) * 8 + (col & 7);
            W3b[dst] = f2bf(W3[idx] * inv);
        }
        if (idx < 196608) {
            int row = idx >> 9, col = idx & 511;
            int dst = (((row >> 4) * 16 + (col >> 5)) * 64 + ((col >> 3) & 3) * 16 + (row & 15)) * 8 + (col & 7);
            W4b[dst] = f2bf(W4[idx]);
        }
        if (idx < 32768) {
            int row = idx >> 7, col = idx & 127;
            int dst = (((row >> 4) * 4 + (col >> 5)) * 64 + ((col >> 3) & 3) * 16 + (row & 15)) * 8 + (col & 7);
            W2b[dst] = f2bf(W2[idx]);
        }
        if (idx < 384) {
            int c = idx / 3;
            float inv = g1[c] / sqrtf(v1[c] + EPS);
            W1f[idx] = W1[idx] * inv;
        }
        if (idx < 128) {
            float inv = g1[idx] / sqrtf(v1[idx] + EPS);
            b1p[idx] = b1[idx] * inv + be1[idx] - m1[idx] * inv;
        }
        if (idx < 512) {
            float inv = g3[idx] / sqrtf(v3[idx] + EPS);
            b3p[idx] = b3[idx] * inv + be3[idx] - m3[idx] * inv;
        }
    }
}

// LDS map (68 KB, 2 blocks/CU):
//   HT  [0,16K)       hT   64 cols x 128 ch bf16 (stride 256B)
//   PF  [16K,48K)     pf   64 cols x 256 ch bf16 (stride 512B)
//   GFT [48K,56K)     gf   16 cols x 256 ch bf16 (stride 512B; cols 0,1 = groups)
//   H2  [0,64K)       h2   64 cols x 512 ch bf16 (stride 1024B) ALIASES HT/PF/GFT,
//                     written only after the post-L3 barrier
//   U   [64K,68K)     u    2 groups x 512 f32 (W3a @ gf)
#define OFF_HT  0
#define OFF_PF  16384
#define OFF_GFT 49152
#define OFF_H2  0
#define OFF_U   65536
#define SMEM_BYTES 69632

__global__ __launch_bounds__(512, 4)
void patch_kernel(const float* __restrict__ pg,
                  const float* __restrict__ b2,
                  const float* __restrict__ b4,
                  const char* __restrict__ ws,
                  float* __restrict__ out)
{
    const float* W1f = (const float*)ws;
    const float* b1p = (const float*)(ws + 1536);
    const float* b3p = (const float*)(ws + 2048);
    const unsigned short* W2b = (const unsigned short*)(ws + 4096);
    const unsigned short* W3b = (const unsigned short*)(ws + 69632);
    const unsigned short* W4b = (const unsigned short*)(ws + 593920);

    __shared__ char smem[SMEM_BYTES];

    const int tid  = (int)threadIdx.x;
    const int wave = tid >> 6;
    const int lane = tid & 63;
    const int l15  = lane & 15;
    const int lq   = lane >> 4;
    const int n0   = (int)blockIdx.x * 2;
    const int M    = (l15 & 7) << 4;          // XOR-swizzle mask (col&7 == l15&7 for all tiles)
    const int bHT  = l15 * 256  + lq * 16;
    const int bPF  = l15 * 512  + lq * 16;
    const int bH2  = l15 * 1024 + lq * 16;

    // ---- Layer 1 (fp32): hT[col][128] ----
    {
        const int col = lane;
        const int g = col >> 5, k = col & 31;
        const float* xp = pg + ((size_t)(n0 + g) * 32 + k) * 3;
        const float x0 = xp[0], x1 = xp[1], x2 = xp[2];
        const int c0 = wave * 16;
        us8 p0, p1;
        #pragma unroll
        for (int j = 0; j < 16; ++j) {
            const int c = c0 + j;
            float v = fmaf(W1f[c*3+0], x0, fmaf(W1f[c*3+1], x1, fmaf(W1f[c*3+2], x2, b1p[c])));
            v = fmaxf(v, 0.f);
            if (j < 8) p0[j] = f2bf(v); else p1[j-8] = f2bf(v);
        }
        *(us8*)(smem + OFF_HT + ((col*256 + c0*2)      ^ ((col & 7) << 4))) = p0;
        *(us8*)(smem + OFF_HT + ((col*256 + c0*2 + 16) ^ ((col & 7) << 4))) = p1;
    }
    __syncthreads();

    // ---- Layer 2 (MFMA, K=128): pf + per-group max -> gf tile ----
    {
        const unsigned short* pA[2];
        #pragma unroll
        for (int mt = 0; mt < 2; ++mt) pA[mt] = W2b + (wave*2 + mt)*2048 + lane*8;

        f32x4 acc[2][4];
        #pragma unroll
        for (int mt = 0; mt < 2; ++mt)
            #pragma unroll
            for (int nt = 0; nt < 4; ++nt) acc[mt][nt] = (f32x4){0.f,0.f,0.f,0.f};

        bf16x8 Ac[2];
        #pragma unroll
        for (int mt = 0; mt < 2; ++mt) Ac[mt] = *(const bf16x8*)(pA[mt]);

        #pragma unroll
        for (int ks = 0; ks < 4; ++ks) {
            bf16x8 Bv[4], An[2];
            #pragma unroll
            for (int nt = 0; nt < 4; ++nt)
                Bv[nt] = *(const bf16x8*)(smem + OFF_HT + ((bHT + nt*4096 + ks*64) ^ M));
            if (ks < 3) {
                #pragma unroll
                for (int mt = 0; mt < 2; ++mt) An[mt] = *(const bf16x8*)(pA[mt] + (ks+1)*512);
            }
            #pragma unroll
            for (int mt = 0; mt < 2; ++mt)
                #pragma unroll
                for (int nt = 0; nt < 4; ++nt)
                    acc[mt][nt] = __builtin_amdgcn_mfma_f32_16x16x32_bf16(Ac[mt], Bv[nt], acc[mt][nt], 0, 0, 0);
            if (ks < 3) {
                #pragma unroll
                for (int mt = 0; mt < 2; ++mt) Ac[mt] = An[mt];
            }
        }

        #pragma unroll
        for (int mt = 0; mt < 2; ++mt) {
            const int row0 = (wave*2 + mt)*16 + lq*4;
            float bias[4];
            #pragma unroll
            for (int r = 0; r < 4; ++r) bias[r] = b2[row0 + r];
            float gmax[2][4];
            #pragma unroll
            for (int nt = 0; nt < 4; ++nt) {
                const int g = nt >> 1;
                us4 p;
                #pragma unroll
                for (int r = 0; r < 4; ++r) {
                    float v = acc[mt][nt][r] + bias[r];
                    p[r] = f2bf(v);
                    if ((nt & 1) == 0) gmax[g][r] = v; else gmax[g][r] = fmaxf(gmax[g][r], v);
                }
                *(us4*)(smem + OFF_PF + ((nt*8192 + l15*512 + row0*2) ^ M)) = p;
            }
            #pragma unroll
            for (int m = 1; m < 16; m <<= 1)
                #pragma unroll
                for (int g = 0; g < 2; ++g)
                    #pragma unroll
                    for (int r = 0; r < 4; ++r)
                        gmax[g][r] = fmaxf(gmax[g][r], __shfl_xor(gmax[g][r], m));
            if (l15 < 2) {
                us4 q;
                #pragma unroll
                for (int r = 0; r < 4; ++r) q[r] = f2bf(gmax[l15][r]);
                *(us4*)(smem + OFF_GFT + ((l15*512 + row0*2) ^ (l15 << 4))) = q;
            }
        }
    }
    __syncthreads();

    // ---- u = W3[:,0:256] @ gf  via N=16 MFMA (cols 0,1 used) ----
    {
        const unsigned short* pA[4];
        #pragma unroll
        for (int mt = 0; mt < 4; ++mt) pA[mt] = W3b + (wave*4 + mt)*8192 + lane*8;

        f32x4 au[4];
        #pragma unroll
        for (int mt = 0; mt < 4; ++mt) au[mt] = (f32x4){0.f,0.f,0.f,0.f};

        #pragma unroll
        for (int ks = 0; ks < 8; ++ks) {
            bf16x8 Bg = *(const bf16x8*)(smem + OFF_GFT + ((l15*512 + lq*16 + ks*64) ^ M));
            #pragma unroll
            for (int mt = 0; mt < 4; ++mt) {
                bf16x8 A = *(const bf16x8*)(pA[mt] + ks*512);
                au[mt] = __builtin_amdgcn_mfma_f32_16x16x32_bf16(A, Bg, au[mt], 0, 0, 0);
            }
        }
        if (l15 < 2) {
            float* u = (float*)(smem + OFF_U);
            #pragma unroll
            for (int mt = 0; mt < 4; ++mt)
                #pragma unroll
                for (int r = 0; r < 4; ++r)
                    u[l15*512 + (wave*4 + mt)*16 + lq*4 + r] = au[mt][r];
        }
    }

    // ---- Layer 3 (MFMA, K=256 over pf): acc, barrier, h2 = relu(acc + b3p + u) ----
    {
        const unsigned short* pA[4];
        #pragma unroll
        for (int mt = 0; mt < 4; ++mt) pA[mt] = W3b + (wave*4 + mt)*8192 + 8*512 + lane*8;

        f32x4 acc[4][4];
        #pragma unroll
        for (int mt = 0; mt < 4; ++mt)
            #pragma unroll
            for (int nt = 0; nt < 4; ++nt) acc[mt][nt] = (f32x4){0.f,0.f,0.f,0.f};

        bf16x8 Ac[4];
        #pragma unroll
        for (int mt = 0; mt < 4; ++mt) Ac[mt] = *(const bf16x8*)(pA[mt]);

        #pragma unroll
        for (int ks = 0; ks < 8; ++ks) {
            bf16x8 Bv[4], An[4];
            #pragma unroll
            for (int nt = 0; nt < 4; ++nt)
                Bv[nt] = *(const bf16x8*)(smem + OFF_PF + ((bPF + nt*8192 + ks*64) ^ M));
            if (ks < 7) {
                #pragma unroll
                for (int mt = 0; mt < 4; ++mt) An[mt] = *(const bf16x8*)(pA[mt] + (ks+1)*512);
            }
            #pragma unroll
            for (int mt = 0; mt < 4; ++mt)
                #pragma unroll
                for (int nt = 0; nt < 4; ++nt)
                    acc[mt][nt] = __builtin_amdgcn_mfma_f32_16x16x32_bf16(Ac[mt], Bv[nt], acc[mt][nt], 0, 0, 0);
            if (ks < 7) {
                #pragma unroll
                for (int mt = 0; mt < 4; ++mt) Ac[mt] = An[mt];
            }
        }

        // all pf/gf reads done; u published; h2 may now overwrite aliased region
        __syncthreads();

        const float* u = (const float*)(smem + OFF_U);
        #pragma unroll
        for (int mt = 0; mt < 4; ++mt) {
            const int row0 = (wave*4 + mt)*16 + lq*4;
            float bias[2][4];
            #pragma unroll
            for (int r = 0; r < 4; ++r) {
                float b = b3p[row0 + r];
                bias[0][r] = b + u[row0 + r];
                bias[1][r] = b + u[512 + row0 + r];
            }
            #pragma unroll
            for (int nt = 0; nt < 4; ++nt) {
                const int g = nt >> 1;
                us4 p;
                #pragma unroll
                for (int r = 0; r < 4; ++r)
                    p[r] = f2bf(fmaxf(acc[mt][nt][r] + bias[g][r], 0.f));
                *(us4*)(smem + OFF_H2 + ((nt*16384 + l15*1024 + row0*2) ^ M)) = p;
            }
        }
    }
    __syncthreads();

    // ---- Layer 4 (MFMA, K=512): out = max_k (W4 h2 + b4) ----
    {
        const unsigned short* pA[3];
        #pragma unroll
        for (int mt = 0; mt < 3; ++mt) pA[mt] = W4b + (wave*3 + mt)*8192 + lane*8;

        f32x4 acc[3][4];
        #pragma unroll
        for (int mt = 0; mt < 3; ++mt)
            #pragma unroll
            for (int nt = 0; nt < 4; ++nt) acc[mt][nt] = (f32x4){0.f,0.f,0.f,0.f};

        bf16x8 Ac[3];
        #pragma unroll
        for (int mt = 0; mt < 3; ++mt) Ac[mt] = *(const bf16x8*)(pA[mt]);

        #pragma unroll
        for (int ks = 0; ks < 16; ++ks) {
            bf16x8 Bv[4], An[3];
            #pragma unroll
            for (int nt = 0; nt < 4; ++nt)
                Bv[nt] = *(const bf16x8*)(smem + OFF_H2 + ((bH2 + nt*16384 + ks*64) ^ M));
            if (ks < 15) {
                #pragma unroll
                for (int mt = 0; mt < 3; ++mt) An[mt] = *(const bf16x8*)(pA[mt] + (ks+1)*512);
            }
            #pragma unroll
            for (int mt = 0; mt < 3; ++mt)
                #pragma unroll
                for (int nt = 0; nt < 4; ++nt)
                    acc[mt][nt] = __builtin_amdgcn_mfma_f32_16x16x32_bf16(Ac[mt], Bv[nt], acc[mt][nt], 0, 0, 0);
            if (ks < 15) {
                #pragma unroll
                for (int mt = 0; mt < 3; ++mt) Ac[mt] = An[mt];
            }
        }

        #pragma unroll
        for (int mt = 0; mt < 3; ++mt) {
            const int row0 = (wave*3 + mt)*16 + lq*4;
            float bias[4];
            #pragma unroll
            for (int r = 0; r < 4; ++r) bias[r] = b4[row0 + r];
            float gmax[2][4];
            #pragma unroll
            for (int nt = 0; nt < 4; ++nt) {
                const int g = nt >> 1;
                #pragma unroll
                for (int r = 0; r < 4; ++r) {
                    float v = acc[mt][nt][r] + bias[r];
                    if ((nt & 1) == 0) gmax[g][r] = v; else gmax[g][r] = fmaxf(gmax[g][r], v);
                }
            }
            #pragma unroll
            for (int m = 1; m < 16; m <<= 1)
                #pragma unroll
                for (int g = 0; g < 2; ++g)
                    #pragma unroll
                    for (int r = 0; r < 4; ++r)
                        gmax[g][r] = fmaxf(gmax[g][r], __shfl_xor(gmax[g][r], m));
            if (l15 < 2) {
                const int g = l15;
                f32x4 o;
                #pragma unroll
                for (int r = 0; r < 4; ++r) o[r] = gmax[g][r];
                *(f32x4*)(out + (size_t)(n0 + g) * 384 + row0) = o;
            }
        }
    }
}

extern "C" void kernel_launch(void* const* d_in, const int* in_sizes, int n_in,
                              void* d_out, int out_size, void* d_ws, size_t ws_size,
                              hipStream_t stream) {
    const float* pg  = (const float*)d_in[0];
    const float* W1  = (const float*)d_in[1];
    const float* b1  = (const float*)d_in[2];
    const float* g1  = (const float*)d_in[3];
    const float* be1 = (const float*)d_in[4];
    const float* m1  = (const float*)d_in[5];
    const float* v1  = (const float*)d_in[6];
    const float* W2  = (const float*)d_in[7];
    const float* b2  = (const float*)d_in[8];
    const float* W3  = (const float*)d_in[9];
    const float* b3  = (const float*)d_in[10];
    const float* g3  = (const float*)d_in[11];
    const float* be3 = (const float*)d_in[12];
    const float* m3  = (const float*)d_in[13];
    const float* v3  = (const float*)d_in[14];
    const float* W4  = (const float*)d_in[15];
    const float* b4  = (const float*)d_in[16];
    float* out = (float*)d_out;
    char* ws = (char*)d_ws;

    prep_kernel<<<dim3(256), dim3(256), 0, stream>>>(W1, b1, g1, be1, m1, v1, W2,
                                                     W3, b3, g3, be3, m3, v3, W4, ws);
    patch_kernel<<<dim3(4096), dim3(512), 0, stream>>>(pg, b2, b4, ws, out);
    (void)in_sizes; (void)n_in; (void)out_size; (void)ws_size;
}

// Round 4
// 247.379 us; speedup vs baseline: 2.2528x; 1.3960x over previous
//
#include <hip/hip_runtime.h>

#define EPS 1e-5f

typedef __attribute__((ext_vector_type(8))) short bf16x8;   // MFMA A/B frag (8 bf16)
typedef __attribute__((ext_vector_type(4))) float f32x4;    // MFMA C/D frag
typedef __attribute__((ext_vector_type(4))) unsigned short us4;
typedef __attribute__((ext_vector_type(8))) unsigned short us8;

__device__ __forceinline__ unsigned short f2bf(float f) {
    union { float f; unsigned int u; } c; c.f = f;
    unsigned int u = c.u;
    u += 0x7fffu + ((u >> 16) & 1u);
    return (unsigned short)(u >> 16);
}

// ws layout (bytes) — weights stored FRAGMENT-MAJOR:
//   frag index for element (row,col), K-tiles NKS=K/32:
//     dst = (((row>>4)*NKS + (col>>5))*64 + ((col>>3)&3)*16 + (row&15))*8 + (col&7)
//   so a wave's A-frag load is W + (rowblk*NKS + ks)*512 + lane*8  (contiguous 1KB)
//   [0,1536)        W1f   384 f32  (BN1-folded W1)
//   [1536,2048)     b1p   128 f32
//   [2048,4096)     b3p   512 f32  (BN3-folded bias)
//   [4096,69632)    W2f   256x128 bf16 frag  (NKS=4)
//   [69632,593920)  W3f   512x512 bf16 frag  (NKS=16; ks 0..7 = gf cols, 8..15 = pf cols)
//   [593920,987136) W4f   384x512 bf16 frag  (NKS=16)

__global__ void prep_kernel(const float* __restrict__ W1, const float* __restrict__ b1,
                            const float* __restrict__ g1, const float* __restrict__ be1,
                            const float* __restrict__ m1, const float* __restrict__ v1,
                            const float* __restrict__ W2,
                            const float* __restrict__ W3, const float* __restrict__ b3,
                            const float* __restrict__ g3, const float* __restrict__ be3,
                            const float* __restrict__ m3, const float* __restrict__ v3,
                            const float* __restrict__ W4,
                            char* __restrict__ ws)
{
    float* W1f = (float*)ws;
    float* b1p = (float*)(ws + 1536);
    float* b3p = (float*)(ws + 2048);
    unsigned short* W2b = (unsigned short*)(ws + 4096);
    unsigned short* W3b = (unsigned short*)(ws + 69632);
    unsigned short* W4b = (unsigned short*)(ws + 593920);

    const int stride = gridDim.x * blockDim.x;
    for (int idx = blockIdx.x * blockDim.x + threadIdx.x; idx < 262144; idx += stride) {
        {
            int row = idx >> 9, col = idx & 511;
            float inv = g3[row] / sqrtf(v3[row] + EPS);
            int dst = (((row >> 4) * 16 + (col >> 5)) * 64 + ((col >> 3) & 3) * 16 + (row & 15)) * 8 + (col & 7);
            W3b[dst] = f2bf(W3[idx] * inv);
        }
        if (idx < 196608) {
            int row = idx >> 9, col = idx & 511;
            int dst = (((row >> 4) * 16 + (col >> 5)) * 64 + ((col >> 3) & 3) * 16 + (row & 15)) * 8 + (col & 7);
            W4b[dst] = f2bf(W4[idx]);
        }
        if (idx < 32768) {
            int row = idx >> 7, col = idx & 127;
            int dst = (((row >> 4) * 4 + (col >> 5)) * 64 + ((col >> 3) & 3) * 16 + (row & 15)) * 8 + (col & 7);
            W2b[dst] = f2bf(W2[idx]);
        }
        if (idx < 384) {
            int c = idx / 3;
            float inv = g1[c] / sqrtf(v1[c] + EPS);
            W1f[idx] = W1[idx] * inv;
        }
        if (idx < 128) {
            float inv = g1[idx] / sqrtf(v1[idx] + EPS);
            b1p[idx] = b1[idx] * inv + be1[idx] - m1[idx] * inv;
        }
        if (idx < 512) {
            float inv = g3[idx] / sqrtf(v3[idx] + EPS);
            b3p[idx] = b3[idx] * inv + be3[idx] - m3[idx] * inv;
        }
    }
}

// LDS map (68 KB, 2 blocks/CU):
//   HT  [0,16K)       hT   64 cols x 128 ch bf16 (stride 256B)
//   PF  [16K,48K)     pf   64 cols x 256 ch bf16 (stride 512B)
//   GFT [48K,56K)     gf   16 cols x 256 ch bf16 (stride 512B; cols 0,1 = groups)
//   H2  [0,64K)       h2   64 cols x 512 ch bf16 (stride 1024B) ALIASES HT/PF/GFT,
//                     written only after the post-L3 barrier
//   U   [64K,68K)     u    2 groups x 512 f32 (W3a @ gf)
#define OFF_HT  0
#define OFF_PF  16384
#define OFF_GFT 49152
#define OFF_H2  0
#define OFF_U   65536
#define SMEM_BYTES 69632

__global__ __launch_bounds__(512, 4)
void patch_kernel(const float* __restrict__ pg,
                  const float* __restrict__ b2,
                  const float* __restrict__ b4,
                  const char* __restrict__ ws,
                  float* __restrict__ out)
{
    const float* W1f = (const float*)ws;
    const float* b1p = (const float*)(ws + 1536);
    const float* b3p = (const float*)(ws + 2048);
    const unsigned short* W2b = (const unsigned short*)(ws + 4096);
    const unsigned short* W3b = (const unsigned short*)(ws + 69632);
    const unsigned short* W4b = (const unsigned short*)(ws + 593920);

    __shared__ char smem[SMEM_BYTES];

    const int tid  = (int)threadIdx.x;
    const int wave = tid >> 6;
    const int lane = tid & 63;
    const int l15  = lane & 15;
    const int lq   = lane >> 4;
    const int n0   = (int)blockIdx.x * 2;
    const int M    = (l15 & 7) << 4;          // XOR-swizzle mask (col&7 == l15&7 for all tiles)
    const int bHT  = l15 * 256  + lq * 16;
    const int bPF  = l15 * 512  + lq * 16;
    const int bH2  = l15 * 1024 + lq * 16;

    // ---- Layer 1 (fp32): hT[col][128] ----
    {
        const int col = lane;
        const int g = col >> 5, k = col & 31;
        const float* xp = pg + ((size_t)(n0 + g) * 32 + k) * 3;
        const float x0 = xp[0], x1 = xp[1], x2 = xp[2];
        const int c0 = wave * 16;
        us8 p0, p1;
        #pragma unroll
        for (int j = 0; j < 16; ++j) {
            const int c = c0 + j;
            float v = fmaf(W1f[c*3+0], x0, fmaf(W1f[c*3+1], x1, fmaf(W1f[c*3+2], x2, b1p[c])));
            v = fmaxf(v, 0.f);
            if (j < 8) p0[j] = f2bf(v); else p1[j-8] = f2bf(v);
        }
        *(us8*)(smem + OFF_HT + ((col*256 + c0*2)      ^ ((col & 7) << 4))) = p0;
        *(us8*)(smem + OFF_HT + ((col*256 + c0*2 + 16) ^ ((col & 7) << 4))) = p1;
    }
    __syncthreads();

    // ---- Layer 2 (MFMA, K=128): pf + per-group max -> gf tile ----
    {
        f32x4 acc[2][4];
        #pragma unroll
        for (int mt = 0; mt < 2; ++mt)
            #pragma unroll
            for (int nt = 0; nt < 4; ++nt) acc[mt][nt] = (f32x4){0.f,0.f,0.f,0.f};

        #pragma unroll
        for (int ks = 0; ks < 4; ++ks) {
            bf16x8 A[2], Bv[4];
            #pragma unroll
            for (int mt = 0; mt < 2; ++mt)
                A[mt] = *(const bf16x8*)(W2b + ((wave*2 + mt)*4 + ks)*512 + lane*8);
            #pragma unroll
            for (int nt = 0; nt < 4; ++nt)
                Bv[nt] = *(const bf16x8*)(smem + OFF_HT + ((bHT + nt*4096 + ks*64) ^ M));
            #pragma unroll
            for (int mt = 0; mt < 2; ++mt)
                #pragma unroll
                for (int nt = 0; nt < 4; ++nt)
                    acc[mt][nt] = __builtin_amdgcn_mfma_f32_16x16x32_bf16(A[mt], Bv[nt], acc[mt][nt], 0, 0, 0);
        }

        #pragma unroll
        for (int mt = 0; mt < 2; ++mt) {
            const int row0 = (wave*2 + mt)*16 + lq*4;
            float bias[4];
            #pragma unroll
            for (int r = 0; r < 4; ++r) bias[r] = b2[row0 + r];
            float gmax[2][4];
            #pragma unroll
            for (int nt = 0; nt < 4; ++nt) {
                const int g = nt >> 1;
                us4 p;
                #pragma unroll
                for (int r = 0; r < 4; ++r) {
                    float v = acc[mt][nt][r] + bias[r];
                    p[r] = f2bf(v);
                    if ((nt & 1) == 0) gmax[g][r] = v; else gmax[g][r] = fmaxf(gmax[g][r], v);
                }
                *(us4*)(smem + OFF_PF + ((nt*8192 + l15*512 + row0*2) ^ M)) = p;
            }
            #pragma unroll
            for (int m = 1; m < 16; m <<= 1)
                #pragma unroll
                for (int g = 0; g < 2; ++g)
                    #pragma unroll
                    for (int r = 0; r < 4; ++r)
                        gmax[g][r] = fmaxf(gmax[g][r], __shfl_xor(gmax[g][r], m));
            if (l15 < 2) {
                us4 q;
                #pragma unroll
                for (int r = 0; r < 4; ++r) q[r] = f2bf(gmax[l15][r]);
                *(us4*)(smem + OFF_GFT + ((l15*512 + row0*2) ^ (l15 << 4))) = q;
            }
        }
    }
    __syncthreads();

    // ---- u = W3[:,0:256] @ gf  via N=16 MFMA (cols 0,1 used) ----
    {
        f32x4 au[4];
        #pragma unroll
        for (int mt = 0; mt < 4; ++mt) au[mt] = (f32x4){0.f,0.f,0.f,0.f};

        #pragma unroll 2
        for (int ks = 0; ks < 8; ++ks) {
            bf16x8 Bg = *(const bf16x8*)(smem + OFF_GFT + ((l15*512 + lq*16 + ks*64) ^ M));
            #pragma unroll
            for (int mt = 0; mt < 4; ++mt) {
                bf16x8 A = *(const bf16x8*)(W3b + ((wave*4 + mt)*16 + ks)*512 + lane*8);
                au[mt] = __builtin_amdgcn_mfma_f32_16x16x32_bf16(A, Bg, au[mt], 0, 0, 0);
            }
        }
        if (l15 < 2) {
            float* u = (float*)(smem + OFF_U);
            #pragma unroll
            for (int mt = 0; mt < 4; ++mt)
                #pragma unroll
                for (int r = 0; r < 4; ++r)
                    u[l15*512 + (wave*4 + mt)*16 + lq*4 + r] = au[mt][r];
        }
    }

    // ---- Layer 3 (MFMA, K=256 over pf): acc, barrier, h2 = relu(acc + b3p + u) ----
    {
        f32x4 acc[4][4];
        #pragma unroll
        for (int mt = 0; mt < 4; ++mt)
            #pragma unroll
            for (int nt = 0; nt < 4; ++nt) acc[mt][nt] = (f32x4){0.f,0.f,0.f,0.f};

        #pragma unroll 2
        for (int ks = 0; ks < 8; ++ks) {
            bf16x8 A[4], Bv[4];
            #pragma unroll
            for (int mt = 0; mt < 4; ++mt)
                A[mt] = *(const bf16x8*)(W3b + ((wave*4 + mt)*16 + 8 + ks)*512 + lane*8);
            #pragma unroll
            for (int nt = 0; nt < 4; ++nt)
                Bv[nt] = *(const bf16x8*)(smem + OFF_PF + ((bPF + nt*8192 + ks*64) ^ M));
            #pragma unroll
            for (int mt = 0; mt < 4; ++mt)
                #pragma unroll
                for (int nt = 0; nt < 4; ++nt)
                    acc[mt][nt] = __builtin_amdgcn_mfma_f32_16x16x32_bf16(A[mt], Bv[nt], acc[mt][nt], 0, 0, 0);
        }

        // all pf/gf reads done; u published; h2 may now overwrite aliased region
        __syncthreads();

        const float* u = (const float*)(smem + OFF_U);
        #pragma unroll
        for (int mt = 0; mt < 4; ++mt) {
            const int row0 = (wave*4 + mt)*16 + lq*4;
            float bias[2][4];
            #pragma unroll
            for (int r = 0; r < 4; ++r) {
                float b = b3p[row0 + r];
                bias[0][r] = b + u[row0 + r];
                bias[1][r] = b + u[512 + row0 + r];
            }
            #pragma unroll
            for (int nt = 0; nt < 4; ++nt) {
                const int g = nt >> 1;
                us4 p;
                #pragma unroll
                for (int r = 0; r < 4; ++r)
                    p[r] = f2bf(fmaxf(acc[mt][nt][r] + bias[g][r], 0.f));
                *(us4*)(smem + OFF_H2 + ((nt*16384 + l15*1024 + row0*2) ^ M)) = p;
            }
        }
    }
    __syncthreads();

    // ---- Layer 4 (MFMA, K=512): out = max_k (W4 h2 + b4) ----
    {
        f32x4 acc[3][4];
        #pragma unroll
        for (int mt = 0; mt < 3; ++mt)
            #pragma unroll
            for (int nt = 0; nt < 4; ++nt) acc[mt][nt] = (f32x4){0.f,0.f,0.f,0.f};

        #pragma unroll 2
        for (int ks = 0; ks < 16; ++ks) {
            bf16x8 A[3], Bv[4];
            #pragma unroll
            for (int mt = 0; mt < 3; ++mt)
                A[mt] = *(const bf16x8*)(W4b + ((wave*3 + mt)*16 + ks)*512 + lane*8);
            #pragma unroll
            for (int nt = 0; nt < 4; ++nt)
                Bv[nt] = *(const bf16x8*)(smem + OFF_H2 + ((bH2 + nt*16384 + ks*64) ^ M));
            #pragma unroll
            for (int mt = 0; mt < 3; ++mt)
                #pragma unroll
                for (int nt = 0; nt < 4; ++nt)
                    acc[mt][nt] = __builtin_amdgcn_mfma_f32_16x16x32_bf16(A[mt], Bv[nt], acc[mt][nt], 0, 0, 0);
        }

        #pragma unroll
        for (int mt = 0; mt < 3; ++mt) {
            const int row0 = (wave*3 + mt)*16 + lq*4;
            float bias[4];
            #pragma unroll
            for (int r = 0; r < 4; ++r) bias[r] = b4[row0 + r];
            float gmax[2][4];
            #pragma unroll
            for (int nt = 0; nt < 4; ++nt) {
                const int g = nt >> 1;
                #pragma unroll
                for (int r = 0; r < 4; ++r) {
                    float v = acc[mt][nt][r] + bias[r];
                    if ((nt & 1) == 0) gmax[g][r] = v; else gmax[g][r] = fmaxf(gmax[g][r], v);
                }
            }
            #pragma unroll
            for (int m = 1; m < 16; m <<= 1)
                #pragma unroll
                for (int g = 0; g < 2; ++g)
                    #pragma unroll
                    for (int r = 0; r < 4; ++r)
                        gmax[g][r] = fmaxf(gmax[g][r], __shfl_xor(gmax[g][r], m));
            if (l15 < 2) {
                const int g = l15;
                f32x4 o;
                #pragma unroll
                for (int r = 0; r < 4; ++r) o[r] = gmax[g][r];
                *(f32x4*)(out + (size_t)(n0 + g) * 384 + row0) = o;
            }
        }
    }
}

extern "C" void kernel_launch(void* const* d_in, const int* in_sizes, int n_in,
                              void* d_out, int out_size, void* d_ws, size_t ws_size,
                              hipStream_t stream) {
    const float* pg  = (const float*)d_in[0];
    const float* W1  = (const float*)d_in[1];
    const float* b1  = (const float*)d_in[2];
    const float* g1  = (const float*)d_in[3];
    const float* be1 = (const float*)d_in[4];
    const float* m1  = (const float*)d_in[5];
    const float* v1  = (const float*)d_in[6];
    const float* W2  = (const float*)d_in[7];
    const float* b2  = (const float*)d_in[8];
    const float* W3  = (const float*)d_in[9];
    const float* b3  = (const float*)d_in[10];
    const float* g3  = (const float*)d_in[11];
    const float* be3 = (const float*)d_in[12];
    const float* m3  = (const float*)d_in[13];
    const float* v3  = (const float*)d_in[14];
    const float* W4  = (const float*)d_in[15];
    const float* b4  = (const float*)d_in[16];
    float* out = (float*)d_out;
    char* ws = (char*)d_ws;

    prep_kernel<<<dim3(256), dim3(256), 0, stream>>>(W1, b1, g1, be1, m1, v1, W2,
                                                     W3, b3, g3, be3, m3, v3, W4, ws);
    patch_kernel<<<dim3(4096), dim3(512), 0, stream>>>(pg, b2, b4, ws, out);
    (void)in_sizes; (void)n_in; (void)out_size; (void)ws_size;
}